// Round 5
// baseline (408.811 us; speedup 1.0000x reference)
//
#include <hip/hip_runtime.h>
#include <math.h>

// Problem constants (B=2, T=2048, C=2048, 16 heads, 4 KV heads, HD=128)
#define NB 2
#define T_SEQ 2048
#define C_DIM 2048
#define NH 16
#define NKV 4
#define HD 128
#define KV_DIM (NKV * HD)   // 512
#define M_ROWS (NB * T_SEQ) // 4096

typedef short bf16w8 __attribute__((ext_vector_type(8)));   // MFMA A/B frag (8 bf16)
typedef float f32x4 __attribute__((ext_vector_type(4)));    // 16x16 C/D frag
typedef float f32x16 __attribute__((ext_vector_type(16)));  // 32x32 C/D frag
typedef unsigned short u16x8 __attribute__((ext_vector_type(8)));
typedef unsigned short u16x4 __attribute__((ext_vector_type(4)));

__device__ __forceinline__ unsigned short f2bf(float x) {
  union { float f; unsigned u; } v; v.f = x;
  return (unsigned short)((v.u + 0x7FFFu + ((v.u >> 16) & 1u)) >> 16);
}

// packed bf16 pair: low = lo, high = hi
__device__ __forceinline__ unsigned int cvt_pk_bf16(float lo, float hi) {
  unsigned int r;
  asm("v_cvt_pk_bf16_f32 %0, %1, %2" : "=v"(r) : "v"(lo), "v"(hi));
  return r;
}

__device__ __forceinline__ float wave_reduce_sum(float v) {
#pragma unroll
  for (int off = 32; off > 0; off >>= 1) v += __shfl_xor(v, off, 64);
  return v;
}

// ---------------------------------------------------------------------------
// fp32 -> bf16 bulk convert (16B stores). n8 = elems/8, sizes divisible by 8.
// ---------------------------------------------------------------------------
__global__ __launch_bounds__(256) void cvt_f32_bf16(
    const float* __restrict__ in, unsigned short* __restrict__ out, int n8) {
  int i = blockIdx.x * 256 + threadIdx.x;
  if (i >= n8) return;
  float4 a = ((const float4*)in)[i * 2];
  float4 b = ((const float4*)in)[i * 2 + 1];
  u16x8 o;
  o[0] = f2bf(a.x); o[1] = f2bf(a.y); o[2] = f2bf(a.z); o[3] = f2bf(a.w);
  o[4] = f2bf(b.x); o[5] = f2bf(b.y); o[6] = f2bf(b.z); o[7] = f2bf(b.w);
  *(u16x8*)(out + (size_t)i * 8) = o;
}

// ---------------------------------------------------------------------------
// RoPE cos/sin tables: [T][64] each. theta = 500000.
// ---------------------------------------------------------------------------
__global__ void rope_tables(float* __restrict__ cost, float* __restrict__ sint) {
  int t = blockIdx.x;
  int i = threadIdx.x; // 0..63
  float inv_freq = powf(500000.0f, -(float)i / 64.0f);
  float ang = (float)t * inv_freq;
  cost[t * 64 + i] = cosf(ang);
  sint[t * 64 + i] = sinf(ang);
}

// ---------------------------------------------------------------------------
// GEMM (m97 structure): C[M][N] = A[M][K] * W[N][K]^T, A/W bf16, C fp32.
// 128x128 tile, BK=64, 4 waves (2x2), 4x4 mfma_16x16x32 per wave.
// Staging via global_load_lds width=16 into LINEAR LDS [128][64].
// ---------------------------------------------------------------------------
__global__ __launch_bounds__(256) void gemm_lds_bf16(
    const unsigned short* __restrict__ A, const unsigned short* __restrict__ W,
    float* __restrict__ C, int M, int N, int K) {
  __shared__ __align__(16) unsigned short As[128 * 64];
  __shared__ __align__(16) unsigned short Ws[128 * 64];
  int tid = threadIdx.x;
  int lane = tid & 63;
  int w = tid >> 6;
  int wr = w >> 1, wc = w & 1;
  int l15 = lane & 15, l4 = lane >> 4;

  int segrow = lane >> 3;
  int segk = (lane & 7) * 8;
  const unsigned short* Ag =
      A + (size_t)(blockIdx.y * 128 + w * 32 + segrow) * K + segk;
  const unsigned short* Wg =
      W + (size_t)(blockIdx.x * 128 + w * 32 + segrow) * K + segk;

  f32x4 zero = {0.f, 0.f, 0.f, 0.f};
  f32x4 acc[4][4];
#pragma unroll
  for (int m = 0; m < 4; ++m)
#pragma unroll
    for (int n = 0; n < 4; ++n) acc[m][n] = zero;

  for (int k0 = 0; k0 < K; k0 += 64) {
    __syncthreads();  // previous iteration's LDS reads complete
#pragma unroll
    for (int i = 0; i < 4; ++i) {
      __builtin_amdgcn_global_load_lds(
          (const __attribute__((address_space(1))) void*)(Ag + k0 + (size_t)i * 8 * K),
          (__attribute__((address_space(3))) void*)&As[(w * 32 + i * 8) * 64],
          16, 0, 0);
      __builtin_amdgcn_global_load_lds(
          (const __attribute__((address_space(1))) void*)(Wg + k0 + (size_t)i * 8 * K),
          (__attribute__((address_space(3))) void*)&Ws[(w * 32 + i * 8) * 64],
          16, 0, 0);
    }
    __syncthreads();

    bf16w8 af[2][4], bw[2][4];
#pragma unroll
    for (int kk = 0; kk < 2; ++kk) {
#pragma unroll
      for (int m = 0; m < 4; ++m)
        af[kk][m] = *(const bf16w8*)&As[(wr * 64 + m * 16 + l15) * 64 + kk * 32 + l4 * 8];
#pragma unroll
      for (int n = 0; n < 4; ++n)
        bw[kk][n] = *(const bf16w8*)&Ws[(wc * 64 + n * 16 + l15) * 64 + kk * 32 + l4 * 8];
    }
#pragma unroll
    for (int kk = 0; kk < 2; ++kk)
#pragma unroll
      for (int m = 0; m < 4; ++m)
#pragma unroll
        for (int n = 0; n < 4; ++n)
          acc[m][n] = __builtin_amdgcn_mfma_f32_16x16x32_bf16(
              af[kk][m], bw[kk][n], acc[m][n], 0, 0, 0);
  }

#pragma unroll
  for (int m = 0; m < 4; ++m)
#pragma unroll
    for (int n = 0; n < 4; ++n)
#pragma unroll
      for (int j = 0; j < 4; ++j) {
        int row = blockIdx.y * 128 + wr * 64 + m * 16 + l4 * 4 + j;
        int col = blockIdx.x * 128 + wc * 64 + n * 16 + l15;
        C[(size_t)row * N + col] = acc[m][n][j];
      }
}

// ---------------------------------------------------------------------------
// Per-head RMSNorm + RoPE, fp32 in -> bf16 out (scale folded for Q).
// ---------------------------------------------------------------------------
__global__ __launch_bounds__(256) void norm_rope_bf16(
    const float* __restrict__ X, unsigned short* __restrict__ Y,
    const float* __restrict__ w, const float* __restrict__ cost,
    const float* __restrict__ sint, int nheads, int istride, int ostride,
    float oscale) {
  int wid = (blockIdx.x * 256 + threadIdx.x) >> 6;
  int lane = threadIdx.x & 63;
  int h = wid % nheads;
  int bt = wid / nheads;
  int t = bt & (T_SEQ - 1);
  const float* row = X + (size_t)bt * istride + h * HD;
  float x1 = row[lane];
  float x2 = row[lane + 64];
  float ss = wave_reduce_sum(x1 * x1 + x2 * x2);
  float r = rsqrtf(ss * (1.0f / 128.0f) + 1e-6f);
  x1 = x1 * r * w[lane];
  x2 = x2 * r * w[lane + 64];
  float c = cost[t * 64 + lane];
  float s = sint[t * 64 + lane];
  unsigned short* yrow = Y + (size_t)bt * ostride + h * HD;
  yrow[lane]      = f2bf((x1 * c - x2 * s) * oscale);
  yrow[lane + 64] = f2bf((x2 * c + x1 * s) * oscale);
}

// ---------------------------------------------------------------------------
// V transpose: Vp fp32 rows (stride istride) -> Vt bf16 [(b*512+c)][T].
// ---------------------------------------------------------------------------
__global__ __launch_bounds__(256) void transpose_v(
    const float* __restrict__ Vp, unsigned short* __restrict__ Vt, int istride) {
  __shared__ float tile[64][65];
  int bt_tile = blockIdx.x;           // 0..63  (b*32 + ttile)
  int ct = blockIdx.y;                // 0..7
  int b = bt_tile >> 5;
  int t0 = (bt_tile & 31) * 64;
  int c0 = ct * 64;
  int tid = threadIdx.x;
  int r = tid >> 4;                   // 0..15
  int c4 = (tid & 15) * 4;
#pragma unroll
  for (int p = 0; p < 4; ++p) {
    int row = r + p * 16;
    float4 v = *(const float4*)&Vp[(size_t)(b * T_SEQ + t0 + row) * istride + c0 + c4];
    tile[row][c4] = v.x; tile[row][c4 + 1] = v.y;
    tile[row][c4 + 2] = v.z; tile[row][c4 + 3] = v.w;
  }
  __syncthreads();
#pragma unroll
  for (int p = 0; p < 4; ++p) {
    int drow = r + p * 16;            // local col index = output row
    int cg = c0 + drow;
    u16x4 o;
    o[0] = f2bf(tile[c4 + 0][drow]);
    o[1] = f2bf(tile[c4 + 1][drow]);
    o[2] = f2bf(tile[c4 + 2][drow]);
    o[3] = f2bf(tile[c4 + 3][drow]);
    *(u16x4*)&Vt[(size_t)(b * KV_DIM + cg) * T_SEQ + t0 + c4] = o;
  }
}

// ---------------------------------------------------------------------------
// Causal GQA flash attention v4: swapped-operand 32x32x16 MFMA, in-register
// softmax, no LDS, defer-max, exp2 domain, register double-buffer prefetch,
// tree reductions, GQA-aware block mapping for L1/L2 K/V sharing.
// Block (512 thr, 8 waves): waves 0-3 = 4 Q-heads of one KV head @ qtile jj;
// waves 4-7 = same heads @ qtile 63-jj (uniform 65 iters/block).
// 256 blocks; (p&7)*32+(p>>3) remap pins each (b,kvh) group to one XCD.
// S^T = mfma(A=K, B=Q): col=q=lane&31, row=key=(reg&3)+8*(reg>>2)+4*(lane>>5).
// O^T = mfma(A=V^T, B=P^T): P^T B-frags assembled via cvt_pk + shfl_xor(32).
// ---------------------------------------------------------------------------
__global__ __launch_bounds__(512) void attn_mfma3(
    const unsigned short* __restrict__ Qb, const unsigned short* __restrict__ Kb,
    const unsigned short* __restrict__ Vt, unsigned short* __restrict__ Ob) {
  int lane = threadIdx.x & 63;
  int q31 = lane & 31;
  int hi = lane >> 5;
  int w = threadIdx.x >> 6;           // 0..7

  int p = blockIdx.x;                 // 0..255
  int bidl = (p & 7) * 32 + (p >> 3); // XCD-grouped logical id
  int b = bidl >> 7;
  int kvh = (bidl >> 5) & 3;
  int jj = bidl & 31;
  int side = w >> 2;
  int h = kvh * 4 + (w & 3);
  int qtile = side ? (63 - jj) : jj;
  int q0 = qtile * 32;

  // Q fragments (B-operand): col=q=q31, k = kc*16 + hi*8 + j
  const unsigned short* qptr =
      Qb + ((size_t)(b * T_SEQ + q0 + q31)) * C_DIM + h * HD + hi * 8;
  bf16w8 qf[8];
#pragma unroll
  for (int kc = 0; kc < 8; ++kc) qf[kc] = *(const bf16w8*)(qptr + kc * 16);

  const unsigned short* kptr =
      Kb + ((size_t)(b * T_SEQ)) * KV_DIM + kvh * HD + hi * 8;
  const unsigned short* vptr =
      Vt + ((size_t)(b * KV_DIM + kvh * HD + q31)) * T_SEQ + hi * 8;

  f32x16 acc[4];
#pragma unroll
  for (int dt = 0; dt < 4; ++dt)
#pragma unroll
    for (int r = 0; r < 16; ++r) acc[dt][r] = 0.f;
  float m = -INFINITY, l = 0.f;
  const int ktend = qtile;

  bf16w8 kfA[8], vfA[8], kfB[8], vfB[8];
  // preload kt = 0 into A buffers
  {
    const unsigned short* krow0 = kptr + (size_t)q31 * KV_DIM;
#pragma unroll
    for (int kc = 0; kc < 8; ++kc) kfA[kc] = *(const bf16w8*)(krow0 + kc * 16);
#pragma unroll
    for (int dt = 0; dt < 4; ++dt)
#pragma unroll
      for (int kc = 0; kc < 2; ++kc)
        vfA[dt * 2 + kc] =
            *(const bf16w8*)(vptr + (size_t)dt * 32 * T_SEQ + kc * 16);
  }

  auto process = [&](bf16w8 (&kfC)[8], bf16w8 (&vfC)[8],
                     bf16w8 (&kfN)[8], bf16w8 (&vfN)[8], int kt) {
    // --- prefetch kt+1 (clamped; redundant on last iter) ---
    int ktn = (kt + 1 > ktend) ? ktend : (kt + 1);
    const unsigned short* krow_n = kptr + (size_t)(ktn * 32 + q31) * KV_DIM;
#pragma unroll
    for (int kc = 0; kc < 8; ++kc) kfN[kc] = *(const bf16w8*)(krow_n + kc * 16);
#pragma unroll
    for (int dt = 0; dt < 4; ++dt)
#pragma unroll
      for (int kc = 0; kc < 2; ++kc)
        vfN[dt * 2 + kc] = *(const bf16w8*)(vptr + (size_t)dt * 32 * T_SEQ +
                                            ktn * 32 + kc * 16);

    // --- QK^T: two 4-deep chains then combine ---
    f32x16 sa, sb;
#pragma unroll
    for (int r = 0; r < 16; ++r) { sa[r] = 0.f; sb[r] = 0.f; }
    __builtin_amdgcn_s_setprio(1);
#pragma unroll
    for (int kc = 0; kc < 4; ++kc)
      sa = __builtin_amdgcn_mfma_f32_32x32x16_bf16(kfC[kc], qf[kc], sa, 0, 0, 0);
#pragma unroll
    for (int kc = 4; kc < 8; ++kc)
      sb = __builtin_amdgcn_mfma_f32_32x32x16_bf16(kfC[kc], qf[kc], sb, 0, 0, 0);
    __builtin_amdgcn_s_setprio(0);
    float s[16];
#pragma unroll
    for (int r = 0; r < 16; ++r) s[r] = sa[r] + sb[r];

    if (kt == ktend) {  // diagonal: mask key > q
#pragma unroll
      for (int r = 0; r < 16; ++r) {
        int key = (r & 3) + 8 * (r >> 2) + 4 * hi;
        if (kt * 32 + key > q0 + q31) s[r] = -INFINITY;
      }
    }

    // --- tree max ---
    float tm[8];
#pragma unroll
    for (int i = 0; i < 8; ++i) tm[i] = fmaxf(s[i], s[i + 8]);
#pragma unroll
    for (int i = 0; i < 4; ++i) tm[i] = fmaxf(tm[i], tm[i + 4]);
    float tmax = fmaxf(fmaxf(tm[0], tm[1]), fmaxf(tm[2], tm[3]));
    tmax = fmaxf(tmax, __shfl_xor(tmax, 32, 64));

    if (!__all(tmax <= m + 8.0f)) {   // defer-max (T13)
      float mnew = fmaxf(m, tmax);
      float corr = exp2f(m - mnew);
      l *= corr;
#pragma unroll
      for (int dt = 0; dt < 4; ++dt)
#pragma unroll
        for (int r = 0; r < 16; ++r) acc[dt][r] *= corr;
      m = mnew;
    }

    float pv[16];
#pragma unroll
    for (int r = 0; r < 16; ++r) pv[r] = exp2f(s[r] - m);
    float ts[8];
#pragma unroll
    for (int i = 0; i < 8; ++i) ts[i] = pv[i] + pv[i + 8];
#pragma unroll
    for (int i = 0; i < 4; ++i) ts[i] = ts[i] + ts[i + 4];
    float ps = (ts[0] + ts[1]) + (ts[2] + ts[3]);
    ps += __shfl_xor(ps, 32, 64);
    l += ps;

    unsigned int wk[8];
#pragma unroll
    for (int r = 0; r < 8; ++r) wk[r] = cvt_pk_bf16(pv[2 * r], pv[2 * r + 1]);

    __builtin_amdgcn_s_setprio(1);
#pragma unroll
    for (int kc = 0; kc < 2; ++kc) {
      unsigned int s0 = hi ? wk[4 * kc] : wk[4 * kc + 2];
      unsigned int s1 = hi ? wk[4 * kc + 1] : wk[4 * kc + 3];
      unsigned int z0 = (unsigned int)__shfl_xor((int)s0, 32, 64);
      unsigned int z1 = (unsigned int)__shfl_xor((int)s1, 32, 64);
      union { unsigned int u[4]; bf16w8 v; } pf;
      pf.u[0] = hi ? z0 : wk[4 * kc];
      pf.u[1] = hi ? z1 : wk[4 * kc + 1];
      pf.u[2] = hi ? wk[4 * kc + 2] : z0;
      pf.u[3] = hi ? wk[4 * kc + 3] : z1;
#pragma unroll
      for (int dt = 0; dt < 4; ++dt)
        acc[dt] = __builtin_amdgcn_mfma_f32_32x32x16_bf16(
            vfC[dt * 2 + kc], pf.v, acc[dt], 0, 0, 0);
    }
    __builtin_amdgcn_s_setprio(0);
  };

  int kt = 0;
  for (;;) {
    process(kfA, vfA, kfB, vfB, kt);
    if (++kt > ktend) break;
    process(kfB, vfB, kfA, vfA, kt);
    if (++kt > ktend) break;
  }

  float inv = 1.0f / l;
  // O^T: lane q = q31 fixed; d = dt*32 + 8*(r>>2) + 4*hi + (r&3)
  unsigned short* orow =
      Ob + ((size_t)(b * T_SEQ + q0 + q31)) * C_DIM + h * HD + hi * 4;
#pragma unroll
  for (int dt = 0; dt < 4; ++dt)
#pragma unroll
    for (int rq = 0; rq < 4; ++rq) {
      unsigned int w0 = cvt_pk_bf16(acc[dt][rq * 4 + 0] * inv, acc[dt][rq * 4 + 1] * inv);
      unsigned int w1 = cvt_pk_bf16(acc[dt][rq * 4 + 2] * inv, acc[dt][rq * 4 + 3] * inv);
      uint2 st; st.x = w0; st.y = w1;
      *(uint2*)(orow + dt * 32 + rq * 8) = st;
    }
}

// ---------------------------------------------------------------------------
// Launch
// ---------------------------------------------------------------------------
extern "C" void kernel_launch(void* const* d_in, const int* in_sizes, int n_in,
                              void* d_out, int out_size, void* d_ws, size_t ws_size,
                              hipStream_t stream) {
  const float* x  = (const float*)d_in[0];
  const float* wq = (const float*)d_in[1];
  const float* wk = (const float*)d_in[2];
  const float* wv = (const float*)d_in[3];
  const float* wo = (const float*)d_in[4];
  const float* qw = (const float*)d_in[5];
  const float* kw = (const float*)d_in[6];
  float* out = (float*)d_out;

  char* p = (char*)d_ws;
  auto alloc = [&](size_t bytes) { void* r = (void*)p; p += (bytes + 255) & ~(size_t)255; return r; };
  float* qp   = (float*)alloc((size_t)M_ROWS * C_DIM * 4);
  float* kvp  = (float*)alloc((size_t)M_ROWS * 2 * KV_DIM * 4);  // K | V fused
  float* cost = (float*)alloc((size_t)T_SEQ * 64 * 4);
  float* sint = (float*)alloc((size_t)T_SEQ * 64 * 4);
  unsigned short* xb   = (unsigned short*)alloc((size_t)M_ROWS * C_DIM * 2);
  unsigned short* wqb  = (unsigned short*)alloc((size_t)C_DIM * C_DIM * 2);
  unsigned short* wkvb = (unsigned short*)alloc((size_t)2 * KV_DIM * C_DIM * 2);
  unsigned short* wob  = (unsigned short*)alloc((size_t)C_DIM * C_DIM * 2);
  unsigned short* qb   = (unsigned short*)alloc((size_t)M_ROWS * C_DIM * 2);
  unsigned short* kb   = (unsigned short*)alloc((size_t)M_ROWS * KV_DIM * 2);
  unsigned short* vt   = (unsigned short*)alloc((size_t)M_ROWS * KV_DIM * 2);
  unsigned short* attb = (unsigned short*)alloc((size_t)M_ROWS * C_DIM * 2);

  dim3 blk(256);
  rope_tables<<<dim3(T_SEQ), dim3(64), 0, stream>>>(cost, sint);

  // bf16 conversions (wk|wv concatenated -> fused KV weight [1024][2048])
  cvt_f32_bf16<<<dim3(M_ROWS * C_DIM / 2048), blk, 0, stream>>>(x, xb, M_ROWS * C_DIM / 8);
  cvt_f32_bf16<<<dim3(C_DIM * C_DIM / 2048), blk, 0, stream>>>(wq, wqb, C_DIM * C_DIM / 8);
  cvt_f32_bf16<<<dim3(KV_DIM * C_DIM / 2048), blk, 0, stream>>>(wk, wkvb, KV_DIM * C_DIM / 8);
  cvt_f32_bf16<<<dim3(KV_DIM * C_DIM / 2048), blk, 0, stream>>>(
      wv, wkvb + (size_t)KV_DIM * C_DIM, KV_DIM * C_DIM / 8);
  cvt_f32_bf16<<<dim3(C_DIM * C_DIM / 2048), blk, 0, stream>>>(wo, wob, C_DIM * C_DIM / 8);

  // Projections (m97-structure bf16 MFMA, fp32 out)
  gemm_lds_bf16<<<dim3(C_DIM / 128, M_ROWS / 128), blk, 0, stream>>>(
      xb, wqb, qp, M_ROWS, C_DIM, C_DIM);
  gemm_lds_bf16<<<dim3(2 * KV_DIM / 128, M_ROWS / 128), blk, 0, stream>>>(
      xb, wkvb, kvp, M_ROWS, 2 * KV_DIM, C_DIM);

  // RMSNorm + RoPE -> bf16. Q scale folds 1/sqrt(HD) AND log2(e) (exp2 domain).
  const float qscale = 0.08838834764831845f * 1.4426950408889634f;
  norm_rope_bf16<<<dim3(M_ROWS * NH / 4), blk, 0, stream>>>(
      qp, qb, qw, cost, sint, NH, C_DIM, C_DIM, qscale);
  norm_rope_bf16<<<dim3(M_ROWS * NKV / 4), blk, 0, stream>>>(
      kvp, kb, kw, cost, sint, NKV, 2 * KV_DIM, KV_DIM, 1.0f);

  // V (second half of fused KV) -> transposed bf16 (V^T)
  transpose_v<<<dim3(M_ROWS / 64, KV_DIM / 64), blk, 0, stream>>>(
      kvp + KV_DIM, vt, 2 * KV_DIM);

  // Flash attention v4: 256 blocks x 8 waves, GQA-grouped, prefetched
  attn_mfma3<<<dim3(256), dim3(512), 0, stream>>>(qb, kb, vt, attb);

  // Output projection
  gemm_lds_bf16<<<dim3(C_DIM / 128, M_ROWS / 128), blk, 0, stream>>>(
      attb, wob, out, M_ROWS, C_DIM, C_DIM);
}